// Round 3
// baseline (342.248 us; speedup 1.0000x reference)
//
#include <hip/hip_runtime.h>
#include <math.h>

// RPNLayer: logits = x(32768,1024) @ W(1024,16) + b; per-anchor (8) 2-class
// CE over valid anchors; argmax + candidate mask.
//
// R3: LDS-pipe was the R2 bottleneck (9.2k b128 reads/CU = 46 us vs 21 us HBM).
// Fix: 8-row x 8-ch register tile per lane -> LDS floats/FMA 1.125 -> 0.25.
// Lane (tid) = k-subgroup g = tid>>3 (4 consecutive k per chunk), row-group
// rg = (tid&7)>>1 (rows rg+4i), ch-half cg = tid&1. Partials combined via
// ds_add_f32 atomics into a bias-initialized 2KB block accumulator.
//
// d_out (float32): [0] loss | [1..262144] predict | [262145..524288] mask

#define ROWS 32
#define CK   128          // K per staging chunk
#define NCH  8            // 1024 / CK

__global__ __launch_bounds__(256, 4)
void rpn_main(const float* __restrict__ x, const float* __restrict__ W,
              const float* __restrict__ b, const int* __restrict__ lab,
              float* __restrict__ out, float* __restrict__ ws)
{
    __shared__ __align__(16) float xs[ROWS * CK];   // 16 KB
    __shared__ __align__(16) float wlds[CK * 16];   // 8 KB
    __shared__ float red[ROWS * 16];                // 2 KB block accumulator
    __shared__ float lossred[2];

    const int tid = threadIdx.x;
    const int g   = tid >> 3;        // k-subgroup: chunk-local k in [g*4, g*4+4)
    const int rg  = (tid & 7) >> 1;  // rows rg, rg+4, ..., rg+28
    const int cg  = tid & 1;         // channels cg*8 .. cg*8+7
    const int row0 = blockIdx.x * ROWS;

    // bias-init block accumulator (atomics add partials onto it)
    red[tid]       = b[tid & 15];
    red[tid + 256] = b[tid & 15];
    if (tid < 2) lossred[tid] = 0.f;

    const float* gx = x + (size_t)row0 * 1024;

    float acc[8][8];
#pragma unroll
    for (int i = 0; i < 8; ++i)
#pragma unroll
        for (int c = 0; c < 8; ++c) acc[i][c] = 0.f;

    // register-prefetch of the x chunk (4 float4 / thread)
    float4 xv[4];
#pragma unroll
    for (int j = 0; j < 4; ++j) {
        int fl = j * 256 + tid;
        xv[j] = *(const float4*)(gx + (size_t)(fl >> 5) * 1024 + (fl & 31) * 4);
    }

    for (int c = 0; c < NCH; ++c) {
        __syncthreads();   // previous compute done; xs/wlds reusable
        // ---- stage x from prefetch regs ----
#pragma unroll
        for (int j = 0; j < 4; ++j)
            *(float4*)(xs + (j * 256 + tid) * 4) = xv[j];
        // ---- stage W chunk (contiguous 8 KB), 2 float4 / thread ----
#pragma unroll
        for (int j = 0; j < 2; ++j) {
            int fl = j * 256 + tid;
            float4 wv = *(const float4*)(W + c * (CK * 16) + fl * 4);
            *(float4*)(wlds + fl * 4) = wv;
        }
        __syncthreads();
        // ---- prefetch next x chunk (in flight during compute) ----
        if (c + 1 < NCH) {
#pragma unroll
            for (int j = 0; j < 4; ++j) {
                int fl = j * 256 + tid;
                xv[j] = *(const float4*)(gx + (size_t)(fl >> 5) * 1024
                                            + (c + 1) * CK + (fl & 31) * 4);
            }
        }
        // ---- compute: 8 rows x 8 ch x 4 k per lane = 256 FMA ----
        const float* xp = xs + rg * CK + g * 4;
        const float* wp = wlds + g * 64 + cg * 8;
        float4 wa[4], wb[4];
#pragma unroll
        for (int dk = 0; dk < 4; ++dk) {
            wa[dk] = *(const float4*)(wp + dk * 16);
            wb[dk] = *(const float4*)(wp + dk * 16 + 4);
        }
#pragma unroll
        for (int i = 0; i < 8; ++i) {
            float4 xq = *(const float4*)(xp + i * (4 * CK));
            float xk[4] = {xq.x, xq.y, xq.z, xq.w};
#pragma unroll
            for (int dk = 0; dk < 4; ++dk) {
                acc[i][0] = fmaf(xk[dk], wa[dk].x, acc[i][0]);
                acc[i][1] = fmaf(xk[dk], wa[dk].y, acc[i][1]);
                acc[i][2] = fmaf(xk[dk], wa[dk].z, acc[i][2]);
                acc[i][3] = fmaf(xk[dk], wa[dk].w, acc[i][3]);
                acc[i][4] = fmaf(xk[dk], wb[dk].x, acc[i][4]);
                acc[i][5] = fmaf(xk[dk], wb[dk].y, acc[i][5]);
                acc[i][6] = fmaf(xk[dk], wb[dk].z, acc[i][6]);
                acc[i][7] = fmaf(xk[dk], wb[dk].w, acc[i][7]);
            }
        }
    }

    // ---- combine 32 k-subgroup partials per output via LDS f32 atomics ----
#pragma unroll
    for (int i = 0; i < 8; ++i) {
        int rbase = (rg + 4 * i) * 16 + cg * 8;
#pragma unroll
        for (int cc = 0; cc < 8; ++cc)
            atomicAdd(&red[rbase + cc], acc[i][cc]);
    }
    __syncthreads();

    // ---- epilogue: one thread per anchor (32 rows x 8 anchors = 256) ----
    {
        const int row = tid >> 3;
        const int a   = tid & 7;
        float2 l01 = *(const float2*)&red[row * 16 + 2 * a];
        int lb = lab[(size_t)row0 * 8 + tid];
        float l0 = l01.x, l1 = l01.y;
        int pred  = (l1 > l0) ? 1 : 0;           // strict: tie -> class 0
        int valid = (lb != -1);
        float m   = fmaxf(l0, l1);
        float lse = m + logf(expf(l0 - m) + expf(l1 - m));
        float nll = lse - ((lb == 1) ? l1 : l0);
        float ls = valid ? nll : 0.f;
        float lc = valid ? 1.f : 0.f;
        out[1 + (size_t)row0 * 8 + tid] = (float)pred;
        out[1 + 262144 + (size_t)row0 * 8 + tid] = (pred && valid) ? 1.f : 0.f;
#pragma unroll
        for (int off = 32; off > 0; off >>= 1) {
            ls += __shfl_down(ls, off);
            lc += __shfl_down(lc, off);
        }
        if ((tid & 63) == 0) {
            atomicAdd(&lossred[0], ls);
            atomicAdd(&lossred[1], lc);
        }
    }
    __syncthreads();
    if (tid == 0) {
        atomicAdd(&ws[0], lossred[0]);
        atomicAdd(&ws[1], lossred[1]);
    }
}

__global__ void rpn_final(const float* __restrict__ ws, float* __restrict__ out)
{
    out[0] = ws[0] / fmaxf(ws[1], 1.f);
}

extern "C" void kernel_launch(void* const* d_in, const int* in_sizes, int n_in,
                              void* d_out, int out_size, void* d_ws, size_t ws_size,
                              hipStream_t stream)
{
    const float* x   = (const float*)d_in[0];   // (64,512,1024) f32
    const float* W   = (const float*)d_in[1];   // (1024,16) f32
    const float* b   = (const float*)d_in[2];   // (16,) f32
    const int*   lab = (const int*)d_in[3];     // (64,512,8) i32 in {-1,0,1}
    float* out = (float*)d_out;
    float* ws  = (float*)d_ws;

    hipMemsetAsync(ws, 0, 2 * sizeof(float), stream);
    rpn_main<<<dim3(1024), dim3(256), 0, stream>>>(x, W, b, lab, out, ws);
    rpn_final<<<dim3(1), dim3(1), 0, stream>>>(ws, out);
}

// Round 4
// 248.268 us; speedup vs baseline: 1.3785x; 1.3785x over previous
//
#include <hip/hip_runtime.h>
#include <math.h>

// RPNLayer: logits = x(32768,1024) @ W(1024,16) + b; per-anchor (8) 2-class
// CE over valid anchors; argmax + candidate mask.
//
// R4 = R2 skeleton (32 rows/block, 1024 blocks, 4 waves = K-slices of 256,
// lane = (row r, channel-half h), XSTR=36 conflict-free x staging) with ONE
// change: W is read via global broadcast loads (2 addrs/instr, L1-resident
// 16 KB) instead of LDS. R2's LDS pipe was 2x over the HBM roofline purely
// from W re-reads (64 b128/chunk/lane); x reads (8/chunk) stay in LDS.
// R3's register-tile spilled (WRITE_SIZE 151 MB) — reverted.
//
// d_out (float32): [0] loss | [1..262144] predict | [262145..524288] mask

#define ROWS   32
#define KSLICE 256
#define CHUNK  32
#define XSTR   36   // floats; verified 0 bank conflicts in R1/R2

__global__ __launch_bounds__(256, 4)
void rpn_main(const float* __restrict__ x, const float* __restrict__ W,
              const float* __restrict__ b, const int* __restrict__ lab,
              float* __restrict__ out, float* __restrict__ ws)
{
    __shared__ float xs[4 * ROWS * XSTR];    // 4608 floats = 18432 B
    float* red = xs;                         // aliased: lifetimes disjoint

    const int tid  = threadIdx.x;
    const int wave = tid >> 6;
    const int lane = tid & 63;
    const int r    = lane & 31;
    const int h    = lane >> 5;              // channel half: 8 channels each
    const int row0 = blockIdx.x * ROWS;

    float* xslab = xs + wave * (ROWS * XSTR);
    const float* gx = x + (size_t)row0 * 1024 + wave * KSLICE;
    // W pointer for this wave's K-slice and this lane's channel half.
    // Addresses depend only on (wave, h) -> 2 distinct addrs per instr.
    const float* wp = W + wave * (KSLICE * 16) + h * 8;

    float acc[8];
#pragma unroll
    for (int c = 0; c < 8; ++c) acc[c] = 0.f;

    for (int ch = 0; ch < KSLICE / CHUNK; ++ch) {
        // ---- stage x: 32 rows x 32 floats per wave slice, coalesced f4 ----
        const float* gsrc = gx + ch * CHUNK;
#pragma unroll
        for (int j = 0; j < 4; ++j) {
            int fl = j * 64 + lane;          // 256 float4s
            int rr = fl >> 3;
            int c4 = fl & 7;
            float4 v = *(const float4*)(gsrc + (size_t)rr * 1024 + c4 * 4);
            *(float4*)(xslab + rr * XSTR + c4 * 4) = v;
        }
        __syncthreads();

        // ---- compute: lane owns (row r, channels h*8..h*8+7) ----
        const float* xrow = xslab + r * XSTR;
        const float* wch  = wp + ch * (CHUNK * 16);
#pragma unroll 2
        for (int t4 = 0; t4 < CHUNK / 4; ++t4) {
            float4 xq = *(const float4*)(xrow + t4 * 4);
            float xk[4] = {xq.x, xq.y, xq.z, xq.w};
#pragma unroll
            for (int dk = 0; dk < 4; ++dk) {
                const float* wk = wch + (t4 * 4 + dk) * 16;
                float4 wa = *(const float4*)(wk);
                float4 wb = *(const float4*)(wk + 4);
                acc[0] = fmaf(xk[dk], wa.x, acc[0]);
                acc[1] = fmaf(xk[dk], wa.y, acc[1]);
                acc[2] = fmaf(xk[dk], wa.z, acc[2]);
                acc[3] = fmaf(xk[dk], wa.w, acc[3]);
                acc[4] = fmaf(xk[dk], wb.x, acc[4]);
                acc[5] = fmaf(xk[dk], wb.y, acc[5]);
                acc[6] = fmaf(xk[dk], wb.z, acc[6]);
                acc[7] = fmaf(xk[dk], wb.w, acc[7]);
            }
        }
        __syncthreads();
    }

    // ---- write K-slice partials (red aliases xs; all waves past barrier) ----
    {
        float* rp = red + r * 68 + wave * 16 + h * 8;
        *(float4*)(rp)     = make_float4(acc[0], acc[1], acc[2], acc[3]);
        *(float4*)(rp + 4) = make_float4(acc[4], acc[5], acc[6], acc[7]);
    }
    __syncthreads();

    // ---- epilogue: one thread per row (verified in R2) ----
    if (tid < ROWS) {
        const int row = row0 + tid;
        float L[16];
#pragma unroll
        for (int c = 0; c < 16; ++c)
            L[c] = red[tid * 68 + c] + red[tid * 68 + 16 + c]
                 + red[tid * 68 + 32 + c] + red[tid * 68 + 48 + c] + b[c];

        const int* labp  = lab + (size_t)row * 8;
        float*     predp = out + 1 + (size_t)row * 8;
        float*     maskp = out + 1 + 262144 + (size_t)row * 8;

        float lsum = 0.f, lcnt = 0.f;
#pragma unroll
        for (int a = 0; a < 8; ++a) {
            float l0 = L[2 * a], l1 = L[2 * a + 1];
            int   lb = labp[a];
            int   pred  = (l1 > l0) ? 1 : 0;          // strict: tie -> class 0
            int   valid = (lb != -1);
            float m   = fmaxf(l0, l1);
            float lse = m + logf(expf(l0 - m) + expf(l1 - m));
            float nll = lse - ((lb == 1) ? l1 : l0);
            if (valid) { lsum += nll; lcnt += 1.f; }
            predp[a] = (float)pred;
            maskp[a] = (pred && valid) ? 1.f : 0.f;
        }

#pragma unroll
        for (int off = 16; off > 0; off >>= 1) {
            lsum += __shfl_down(lsum, off, 32);
            lcnt += __shfl_down(lcnt, off, 32);
        }
        if (tid == 0) {
            atomicAdd(&ws[0], lsum);
            atomicAdd(&ws[1], lcnt);
        }
    }
}

__global__ void rpn_final(const float* __restrict__ ws, float* __restrict__ out)
{
    out[0] = ws[0] / fmaxf(ws[1], 1.f);
}

extern "C" void kernel_launch(void* const* d_in, const int* in_sizes, int n_in,
                              void* d_out, int out_size, void* d_ws, size_t ws_size,
                              hipStream_t stream)
{
    const float* x   = (const float*)d_in[0];   // (64,512,1024) f32
    const float* W   = (const float*)d_in[1];   // (1024,16) f32
    const float* b   = (const float*)d_in[2];   // (16,) f32
    const int*   lab = (const int*)d_in[3];     // (64,512,8) i32 in {-1,0,1}
    float* out = (float*)d_out;
    float* ws  = (float*)d_ws;

    hipMemsetAsync(ws, 0, 2 * sizeof(float), stream);
    rpn_main<<<dim3(1024), dim3(256), 0, stream>>>(x, W, b, lab, out, ws);
    rpn_final<<<dim3(1), dim3(1), 0, stream>>>(ws, out);
}

// Round 5
// 234.527 us; speedup vs baseline: 1.4593x; 1.0586x over previous
//
#include <hip/hip_runtime.h>
#include <math.h>

// RPNLayer: logits = x(32768,1024) @ W(1024,16) + b; per-anchor (8) 2-class
// CE over valid anchors; argmax + candidate mask.
//
// R5 = R3's register-tile (8 rows x 8 ch x 4 k per thread; W held in 32 VGPRs
// reused across 8 rows -> LDS reads/FMA = 0.086) with R3's three defects fixed:
//   1. launch_bounds (256,3): 168-reg cap, ~140 used -> no spill (R3: 151 MB
//      of scratch WRITE_SIZE at the 128 cap).
//   2. W LDS stride 64 -> 68 floats: R3's W-read had all 32 g-lanes on one
//      4-bank span (8-way serialize); 68 spreads starts by 4g -> conflict-free.
//   3. Reduction over the 32 k-subgroups: 2 shfl_xor rounds (g bits 0,1) +
//      16-lane LDS writes + per-anchor gather, replacing R3's 32-way
//      same-address ds_add_f32 atomics (the 4.2M conflict counter).
//
// d_out (float32): [0] loss | [1..262144] predict | [262145..524288] mask

#define XSTR 132   // xs row stride (floats): 16B-aligned, banks spread by 4*row
#define WSTR 68    // wlds per-g stride: 4g bank starts, conflict-free

__global__ __launch_bounds__(256, 3)
void rpn_main(const float* __restrict__ x, const float* __restrict__ W,
              const float* __restrict__ b, const int* __restrict__ lab,
              float* __restrict__ out, float* __restrict__ ws)
{
    __shared__ __align__(16) float xs[32 * XSTR];     // 16896 B
    __shared__ __align__(16) float wlds[32 * WSTR];   // 8704 B
    __shared__ float lossred[2];
    float* red = xs;    // reused after compute: needs 4096 <= 4224 floats

    const int tid  = threadIdx.x;
    const int lane = tid & 63;
    const int wave = tid >> 6;
    const int g    = tid >> 3;          // k-subgroup: chunk-k = g*4 + dk
    const int rg   = (tid >> 1) & 3;    // rows rg + 4i, i = 0..7
    const int cg   = tid & 1;           // channels cg*8 .. cg*8+7
    const int row0 = blockIdx.x * 32;

    if (tid < 2) lossred[tid] = 0.f;

    const float* gx = x + (size_t)row0 * 1024;

    float acc[8][8];
#pragma unroll
    for (int i = 0; i < 8; ++i)
#pragma unroll
        for (int cc = 0; cc < 8; ++cc) acc[i][cc] = 0.f;

    // prefetch chunk 0 (x: 4 float4/thread; W: 2 float4/thread)
    float4 xv[4], wv[2];
#pragma unroll
    for (int j = 0; j < 4; ++j) {
        int fl = j * 256 + tid;
        xv[j] = *(const float4*)(gx + (size_t)(fl >> 5) * 1024 + (fl & 31) * 4);
    }
#pragma unroll
    for (int j = 0; j < 2; ++j)
        wv[j] = *(const float4*)(W + (j * 256 + tid) * 4);

    for (int c = 0; c < 8; ++c) {
        __syncthreads();
        // ---- store staged chunk to LDS ----
#pragma unroll
        for (int j = 0; j < 4; ++j) {
            int fl = j * 256 + tid;
            *(float4*)(xs + (fl >> 5) * XSTR + (fl & 31) * 4) = xv[j];
        }
#pragma unroll
        for (int j = 0; j < 2; ++j) {
            int f = (j * 256 + tid) * 4;           // flat float idx in chunk
            *(float4*)(wlds + (f >> 6) * WSTR + (f & 63)) = wv[j];
        }
        __syncthreads();
        // ---- prefetch next chunk (in flight during compute) ----
        if (c < 7) {
#pragma unroll
            for (int j = 0; j < 4; ++j) {
                int fl = j * 256 + tid;
                xv[j] = *(const float4*)(gx + (size_t)(fl >> 5) * 1024
                                            + (c + 1) * 128 + (fl & 31) * 4);
            }
#pragma unroll
            for (int j = 0; j < 2; ++j)
                wv[j] = *(const float4*)(W + (c + 1) * 2048 + (j * 256 + tid) * 4);
        }
        // ---- W regs for this thread's 4 k x 16-of-8 ch (reused over 8 rows) ----
        const float* wp = wlds + g * WSTR + cg * 8;
        float4 wa[4], wb[4];
#pragma unroll
        for (int dk = 0; dk < 4; ++dk) {
            wa[dk] = *(const float4*)(wp + dk * 16);
            wb[dk] = *(const float4*)(wp + dk * 16 + 4);
        }
        // ---- compute: 8 rows x 8 ch x 4 k = 256 FMA, 8 LDS b128 ----
        const float* xp = xs + rg * XSTR + g * 4;
#pragma unroll
        for (int i = 0; i < 8; ++i) {
            float4 xq = *(const float4*)(xp + i * 4 * XSTR);
            float xk[4] = {xq.x, xq.y, xq.z, xq.w};
#pragma unroll
            for (int dk = 0; dk < 4; ++dk) {
                acc[i][0] = fmaf(xk[dk], wa[dk].x, acc[i][0]);
                acc[i][1] = fmaf(xk[dk], wa[dk].y, acc[i][1]);
                acc[i][2] = fmaf(xk[dk], wa[dk].z, acc[i][2]);
                acc[i][3] = fmaf(xk[dk], wa[dk].w, acc[i][3]);
                acc[i][4] = fmaf(xk[dk], wb[dk].x, acc[i][4]);
                acc[i][5] = fmaf(xk[dk], wb[dk].y, acc[i][5]);
                acc[i][6] = fmaf(xk[dk], wb[dk].z, acc[i][6]);
                acc[i][7] = fmaf(xk[dk], wb[dk].w, acc[i][7]);
            }
        }
    }
    __syncthreads();   // all compute done; xs reusable as red

    // ---- reduce g bits 0,1 (lane bits 3,4) by butterfly ----
#pragma unroll
    for (int off = 8; off <= 16; off <<= 1)
#pragma unroll
        for (int i = 0; i < 8; ++i)
#pragma unroll
            for (int cc = 0; cc < 8; ++cc)
                acc[i][cc] += __shfl_xor(acc[i][cc], off, 64);

    // lanes {0..7, 32..39} hold quad-sums; write 2 halves per wave
    if ((lane & 24) == 0) {
        float* rp = red + wave * 1024 + (lane >> 5) * 512 + (lane & 7) * 64;
#pragma unroll
        for (int i = 0; i < 8; ++i) {
            *(float4*)(rp + i * 8)     = make_float4(acc[i][0], acc[i][1], acc[i][2], acc[i][3]);
            *(float4*)(rp + i * 8 + 4) = make_float4(acc[i][4], acc[i][5], acc[i][6], acc[i][7]);
        }
    }
    __syncthreads();

    // ---- epilogue: thread = (row = tid>>3, anchor a = tid&7) ----
    {
        const int row = tid >> 3;
        const int a   = tid & 7;
        const int l8  = (row & 3) * 2 + (a >> 2);        // rg*2 + cg
        const int ib  = (row >> 2) * 8 + ((2 * a) & 7);  // i*8 + cc
        float l0 = 0.f, l1 = 0.f;
#pragma unroll
        for (int p = 0; p < 8; ++p) {
            float2 v = *(const float2*)(red + p * 512 + l8 * 64 + ib);
            l0 += v.x; l1 += v.y;
        }
        l0 += b[2 * a]; l1 += b[2 * a + 1];

        int lb = lab[(size_t)row0 * 8 + tid];
        int pred  = (l1 > l0) ? 1 : 0;                   // strict: tie -> class 0
        int valid = (lb != -1);
        float m   = fmaxf(l0, l1);
        float lse = m + logf(expf(l0 - m) + expf(l1 - m));
        float nll = lse - ((lb == 1) ? l1 : l0);
        float ls = valid ? nll : 0.f;
        float lc = valid ? 1.f : 0.f;
        out[1 + (size_t)row0 * 8 + tid] = (float)pred;
        out[1 + 262144 + (size_t)row0 * 8 + tid] = (pred && valid) ? 1.f : 0.f;
#pragma unroll
        for (int off = 32; off > 0; off >>= 1) {
            ls += __shfl_down(ls, off);
            lc += __shfl_down(lc, off);
        }
        if ((tid & 63) == 0) {
            atomicAdd(&lossred[0], ls);
            atomicAdd(&lossred[1], lc);
        }
    }
    __syncthreads();
    if (tid == 0) {
        atomicAdd(&ws[0], lossred[0]);
        atomicAdd(&ws[1], lossred[1]);
    }
}

__global__ void rpn_final(const float* __restrict__ ws, float* __restrict__ out)
{
    out[0] = ws[0] / fmaxf(ws[1], 1.f);
}

extern "C" void kernel_launch(void* const* d_in, const int* in_sizes, int n_in,
                              void* d_out, int out_size, void* d_ws, size_t ws_size,
                              hipStream_t stream)
{
    const float* x   = (const float*)d_in[0];   // (64,512,1024) f32
    const float* W   = (const float*)d_in[1];   // (1024,16) f32
    const float* b   = (const float*)d_in[2];   // (16,) f32
    const int*   lab = (const int*)d_in[3];     // (64,512,8) i32 in {-1,0,1}
    float* out = (float*)d_out;
    float* ws  = (float*)d_ws;

    hipMemsetAsync(ws, 0, 2 * sizeof(float), stream);
    rpn_main<<<dim3(1024), dim3(256), 0, stream>>>(x, W, b, lab, out, ws);
    rpn_final<<<dim3(1), dim3(1), 0, stream>>>(ws, out);
}

// Round 6
// 233.365 us; speedup vs baseline: 1.4666x; 1.0050x over previous
//
#include <hip/hip_runtime.h>
#include <math.h>

// RPNLayer: logits = x(32768,1024) @ W(1024,16) + b; per-anchor (8) 2-class
// CE over valid anchors; argmax + candidate mask.
//
// R6: no LDS in the main loop. Thread tile = 4 rows x 8 ch x 4 k/iter, x and
// W read straight from global as 12 independent dwordx4 loads per iter:
//  - x read exactly once per block (g/t partition K, rg/i partition rows);
//    W (64 KB) is L1/L2-resident broadcast (32 distinct addrs/instr).
//  - acc = 32 regs (R3/R5's 64-reg tile spilled: compiler targeted 6
//    waves/EU, VGPR=84+scratch). amdgpu_waves_per_eu(4,4) pins the
//    allocator at 4 waves/EU (128-reg cap) so it cannot spill-chase.
//  - No main-loop barriers or LDS -> no bank conflicts (R5: 4.45M from the
//    4(rg+g)%32 read pattern), waves stream independently.
// Reduction: butterfly shfl_xor over the 16 k-subgroups (lane bits 0..3),
// then 2.5 KB LDS gather + the R2/R5-verified epilogue.
//
// d_out (float32): [0] loss | [1..262144] predict | [262145..524288] mask

#define REDSTR 20   // red row stride (floats): 80 B, 16B-aligned

__global__ __launch_bounds__(256)
__attribute__((amdgpu_waves_per_eu(4, 4)))
void rpn_main(const float* __restrict__ x, const float* __restrict__ W,
              const float* __restrict__ b, const int* __restrict__ lab,
              float* __restrict__ out, float* __restrict__ ws)
{
    __shared__ float red[32 * REDSTR];   // 2560 B
    __shared__ float lossred[2];

    const int tid = threadIdx.x;
    const int g   = tid & 15;            // k-quad: k = t*64 + g*4 + dk
    const int cg  = (tid >> 4) & 1;      // channel half: cg*8 .. cg*8+7
    const int rg  = tid >> 5;            // row group: rows rg*4 .. rg*4+3
    const int row0 = blockIdx.x * 32;

    if (tid < 2) lossred[tid] = 0.f;

    const float* xp = x + (size_t)(row0 + rg * 4) * 1024 + g * 4;
    const float* wp = W + (size_t)(g * 4) * 16 + cg * 8;

    float acc[4][8];
#pragma unroll
    for (int i = 0; i < 4; ++i)
#pragma unroll
        for (int c = 0; c < 8; ++c) acc[i][c] = 0.f;

    for (int t = 0; t < 16; ++t) {
        // 12 independent global loads; all issue before the vmcnt wait.
        float4 xq[4];
#pragma unroll
        for (int i = 0; i < 4; ++i)
            xq[i] = *(const float4*)(xp + (size_t)i * 1024 + t * 64);
        float4 wa[4], wb[4];
#pragma unroll
        for (int dk = 0; dk < 4; ++dk) {
            const float* wk = wp + (t * 64 + dk) * 16;
            wa[dk] = *(const float4*)(wk);
            wb[dk] = *(const float4*)(wk + 4);
        }
        // 4 rows x 8 ch x 4 k = 128 FMA
#pragma unroll
        for (int i = 0; i < 4; ++i) {
            float xk[4] = {xq[i].x, xq[i].y, xq[i].z, xq[i].w};
#pragma unroll
            for (int dk = 0; dk < 4; ++dk) {
                acc[i][0] = fmaf(xk[dk], wa[dk].x, acc[i][0]);
                acc[i][1] = fmaf(xk[dk], wa[dk].y, acc[i][1]);
                acc[i][2] = fmaf(xk[dk], wa[dk].z, acc[i][2]);
                acc[i][3] = fmaf(xk[dk], wa[dk].w, acc[i][3]);
                acc[i][4] = fmaf(xk[dk], wb[dk].x, acc[i][4]);
                acc[i][5] = fmaf(xk[dk], wb[dk].y, acc[i][5]);
                acc[i][6] = fmaf(xk[dk], wb[dk].z, acc[i][6]);
                acc[i][7] = fmaf(xk[dk], wb[dk].w, acc[i][7]);
            }
        }
    }

    // ---- reduce the 16 k-subgroups: butterfly over lane bits 0..3 ----
#pragma unroll
    for (int off = 1; off <= 8; off <<= 1)
#pragma unroll
        for (int i = 0; i < 4; ++i)
#pragma unroll
            for (int c = 0; c < 8; ++c)
                acc[i][c] += __shfl_xor(acc[i][c], off, 64);

    if ((tid & 15) == 0) {               // one lane per (rg, cg)
        float* rp = red + (rg * 4) * REDSTR + cg * 8;
#pragma unroll
        for (int i = 0; i < 4; ++i) {
            *(float4*)(rp + i * REDSTR)     = make_float4(acc[i][0], acc[i][1], acc[i][2], acc[i][3]);
            *(float4*)(rp + i * REDSTR + 4) = make_float4(acc[i][4], acc[i][5], acc[i][6], acc[i][7]);
        }
    }
    __syncthreads();

    // ---- epilogue: thread = (row = tid>>3, anchor a = tid&7) ----
    {
        const int row = tid >> 3;
        const int a   = tid & 7;
        float l0 = red[row * REDSTR + 2 * a]     + b[2 * a];
        float l1 = red[row * REDSTR + 2 * a + 1] + b[2 * a + 1];

        int lb = lab[(size_t)row0 * 8 + tid];
        int pred  = (l1 > l0) ? 1 : 0;           // strict: tie -> class 0
        int valid = (lb != -1);
        float m   = fmaxf(l0, l1);
        float lse = m + logf(expf(l0 - m) + expf(l1 - m));
        float nll = lse - ((lb == 1) ? l1 : l0);
        float ls = valid ? nll : 0.f;
        float lc = valid ? 1.f : 0.f;
        out[1 + (size_t)row0 * 8 + tid] = (float)pred;
        out[1 + 262144 + (size_t)row0 * 8 + tid] = (pred && valid) ? 1.f : 0.f;
#pragma unroll
        for (int off = 32; off > 0; off >>= 1) {
            ls += __shfl_down(ls, off);
            lc += __shfl_down(lc, off);
        }
        if ((tid & 63) == 0) {
            atomicAdd(&lossred[0], ls);
            atomicAdd(&lossred[1], lc);
        }
    }
    __syncthreads();
    if (tid == 0) {
        atomicAdd(&ws[0], lossred[0]);
        atomicAdd(&ws[1], lossred[1]);
    }
}

__global__ void rpn_final(const float* __restrict__ ws, float* __restrict__ out)
{
    out[0] = ws[0] / fmaxf(ws[1], 1.f);
}

extern "C" void kernel_launch(void* const* d_in, const int* in_sizes, int n_in,
                              void* d_out, int out_size, void* d_ws, size_t ws_size,
                              hipStream_t stream)
{
    const float* x   = (const float*)d_in[0];   // (64,512,1024) f32
    const float* W   = (const float*)d_in[1];   // (1024,16) f32
    const float* b   = (const float*)d_in[2];   // (16,) f32
    const int*   lab = (const int*)d_in[3];     // (64,512,8) i32 in {-1,0,1}
    float* out = (float*)d_out;
    float* ws  = (float*)d_ws;

    hipMemsetAsync(ws, 0, 2 * sizeof(float), stream);
    rpn_main<<<dim3(1024), dim3(256), 0, stream>>>(x, W, b, lab, out, ws);
    rpn_final<<<dim3(1), dim3(1), 0, stream>>>(ws, out);
}